// Round 7
// baseline (100.718 us; speedup 1.0000x reference)
//
#include <hip/hip_runtime.h>
#include <hip/hip_bf16.h>

// LocalCausalAttention: B=2, N=2048, D=1024, H=16, DH=64, WINDOW=64
// out = ( softmax(mask(QK^T*0.125)) V ) Wout^T + bout,  QKV = x Wqkv^T + bqkv
//
// R7: occupancy attack. R6 (128^2, 3 blocks/CU, counted-vmcnt BK=32 dbuf) won at
//   46.7us but all counters low -> latency-bound, overlap-starved (3 blocks/CU,
//   grid==768==3/CU exactly). Keep the R6-verified per-wave structure EXACTLY
//   (same swizzle, same 2-barrier counted-vmcnt loop, per-wave 64x64 out) but
//   shrink tiles to 64M x 128N with 2-wave blocks:
//     QKV grid = 64*24 = 1536 = 6 blocks/CU (LDS 24KB -> exactly 6 fit)
//     outproj grid = 64*8 = 512 = 2 blocks/CU
//   -> 12 decorrelated waves/CU with independent barriers.
//   Epilogue stores reordered ni-innermost (full 128B line per row burst).

typedef __attribute__((ext_vector_type(8))) __bf16 bf16x8;
typedef __attribute__((ext_vector_type(4))) float f32x4;

#define GLOAD16(g, l)                                              \
  __builtin_amdgcn_global_load_lds(                                \
      (const __attribute__((address_space(1))) void*)(g),          \
      (__attribute__((address_space(3))) void*)(l), 16, 0, 0)

#define MFMA16(a, b, c) __builtin_amdgcn_mfma_f32_16x16x32_bf16((a), (b), (c), 0, 0, 0)

// ---------------- fused fp32 -> bf16 convert (x, Wqkv, Wout) ----------------
__global__ __launch_bounds__(256) void cvt3(const float* __restrict__ x,
                                            const float* __restrict__ wqkv,
                                            const float* __restrict__ wout,
                                            __bf16* __restrict__ xb,
                                            __bf16* __restrict__ wqkvb,
                                            __bf16* __restrict__ woutb) {
  const int blk = blockIdx.x;
  const float* src;
  __bf16* dst;
  int i;
  if (blk < 2048) {            // x: 4194304 elems
    src = x; dst = xb; i = (blk * 256 + (int)threadIdx.x) * 8;
  } else if (blk < 3584) {     // Wqkv: 3145728 elems
    src = wqkv; dst = wqkvb; i = ((blk - 2048) * 256 + (int)threadIdx.x) * 8;
  } else {                     // Wout: 1048576 elems
    src = wout; dst = woutb; i = ((blk - 3584) * 256 + (int)threadIdx.x) * 8;
  }
  f32x4 a = *(const f32x4*)(src + i);
  f32x4 b = *(const f32x4*)(src + i + 4);
  bf16x8 o;
  o[0] = (__bf16)a[0]; o[1] = (__bf16)a[1]; o[2] = (__bf16)a[2]; o[3] = (__bf16)a[3];
  o[4] = (__bf16)b[0]; o[5] = (__bf16)b[1]; o[6] = (__bf16)b[2]; o[7] = (__bf16)b[3];
  *(bf16x8*)(dst + i) = o;
}

// ---------------- 64x128 BK=32 double-buffered GEMM, 2 waves ----------------
// C[m,n] = sum_k A[m,k]*Bw[n,k] + bias[n].  2 waves (1Mx2N), per-wave 64x64.
// LDS 24KB: [A0 4K][B0 8K][A1 4K][B1 8K]; paired-row layout, slot-XOR swizzle
// (R6-verified: 0 bank conflicts). Counted vmcnt(6) pipeline, raw barriers.
// MODE 0: scatter bf16 to Q(*0.125)/K/V [B,H,2048,64].  MODE 1: fp32 out + bias.
template <int MODE>
__global__ __launch_bounds__(128) void gemm_db(
    const __bf16* __restrict__ A, const __bf16* __restrict__ Bw,
    const float* __restrict__ bias, int M, int N, int K,
    float* __restrict__ outF,
    __bf16* __restrict__ qo, __bf16* __restrict__ ko, __bf16* __restrict__ vo,
    int nbn, int chunk) {
  __shared__ __align__(16) unsigned char Ls[24576];
  const int tid = threadIdx.x;
  const int lane = tid & 63;
  const int wc = tid >> 6;              // wave n-half (wave grid 1M x 2N)
  const int colL = lane & 15, g = lane >> 4;

  // T1: XCD chunking (grid %8 == 0 -> bijective). n varies fastest inside chunk.
  int s = (int)blockIdx.x;
  s = (s & 7) * chunk + (s >> 3);
  const int m0 = (s / nbn) * 64, n0 = (s % nbn) * 128;

  const __bf16* Ap = A + (size_t)m0 * K;
  const __bf16* Bp = Bw + (size_t)n0 * K;

  // stage NIT*128 16B-chunks (NIT=2: 64 rows x 32 cols; NIT=4: 128 rows x 32 cols)
  // linear LDS dest c*16; line L=c>>3, s6=c&7; u=s6^(L&7) -> row=2L+(u>>2), p=u&3.
  auto stageA = [&](const __bf16* src, unsigned char* lds, int k0) {
#pragma unroll
    for (int it = 0; it < 2; ++it) {
      int c = tid + (it << 7);       // 0..255
      int L = c >> 3, s6 = c & 7;
      int u = s6 ^ (L & 7);
      int row = (L << 1) | (u >> 2), p = u & 3;
      GLOAD16(src + (size_t)row * K + k0 + (p << 3), lds + c * 16);
    }
  };
  auto stageB = [&](const __bf16* src, unsigned char* lds, int k0) {
#pragma unroll
    for (int it = 0; it < 4; ++it) {
      int c = tid + (it << 7);       // 0..511
      int L = c >> 3, s6 = c & 7;
      int u = s6 ^ (L & 7);
      int row = (L << 1) | (u >> 2), p = u & 3;
      GLOAD16(src + (size_t)row * K + k0 + (p << 3), lds + c * 16);
    }
  };

  f32x4 acc[4][4] = {};

  // prologue: tiles 0,1 into bufs 0,1  (6 gloads each)
  stageA(Ap, Ls, 0);
  stageB(Bp, Ls + 4096, 0);
  stageA(Ap, Ls + 12288, 32);
  stageB(Bp, Ls + 16384, 32);
  asm volatile("s_waitcnt vmcnt(6)" ::: "memory");  // tile0 landed; tile1 in flight
  __builtin_amdgcn_s_barrier();

  const int nT = K >> 5;  // 32 steps
  for (int t = 0; t < nT; ++t) {
    const unsigned char* Ab = Ls + (t & 1) * 12288;
    const unsigned char* Bb = Ab + 4096;
    bf16x8 af[4], bf[4];
#pragma unroll
    for (int mi = 0; mi < 4; ++mi) {
      const int r = (mi << 4) + colL;  // 0..63
      af[mi] = *(const bf16x8*)(Ab + (r >> 1) * 128 +
                                (((((r & 1) << 2) | g) ^ ((r >> 1) & 7)) << 4));
    }
#pragma unroll
    for (int ni = 0; ni < 4; ++ni) {
      const int r = (wc << 6) + (ni << 4) + colL;  // 0..127
      bf[ni] = *(const bf16x8*)(Bb + (r >> 1) * 128 +
                                (((((r & 1) << 2) | g) ^ ((r >> 1) & 7)) << 4));
    }
#pragma unroll
    for (int mi = 0; mi < 4; ++mi)
#pragma unroll
      for (int ni = 0; ni < 4; ++ni)
        acc[mi][ni] = MFMA16(af[mi], bf[ni], acc[mi][ni]);
    // all this wave's ds_reads completed before anyone may DMA-overwrite buf[cur]
    asm volatile("s_waitcnt lgkmcnt(0)" ::: "memory");
    __builtin_amdgcn_s_barrier();
    if (t < nT - 2) {
      const int kn = (t + 2) << 5;
      unsigned char* dst = Ls + (t & 1) * 12288;  // overwrite just-retired buffer
      stageA(Ap, dst, kn);
      stageB(Bp, dst + 4096, kn);
      // in flight: tile t+1 (6) + tile t+2 (6); retire oldest 6 -> t+1 validated
      asm volatile("s_waitcnt vmcnt(6)" ::: "memory");
    } else {
      asm volatile("s_waitcnt vmcnt(0)" ::: "memory");  // tail: drain last tile
    }
    __builtin_amdgcn_s_barrier();
  }

  // epilogue: C/D layout col=lane&15, row=(lane>>4)*4+reg (m89-verified).
  // Per wave: whole 64-col half lies in one of Q/K/V and one head -> dst/h/mul const.
  if (MODE == 0) {
    const int Cn0 = n0 + (wc << 6);
    const int sx = Cn0 >> 10, h = (Cn0 >> 6) & 15;
    __bf16* dst = (sx == 0) ? qo : (sx == 1 ? ko : vo);
    const float mul = (sx == 0) ? 0.125f : 1.0f;  // fold SCALE into Q (exact pow2)
    float bv[4];
#pragma unroll
    for (int ni = 0; ni < 4; ++ni) bv[ni] = bias[Cn0 + (ni << 4) + colL];
#pragma unroll
    for (int mi = 0; mi < 4; ++mi) {
#pragma unroll
      for (int j = 0; j < 4; ++j) {
        const int Rm = m0 + (mi << 4) + (g << 2) + j;
        const int bb = Rm >> 11, tt = Rm & 2047;
        __bf16* rowp = dst + (((size_t)bb * 16 + h) * 2048 + tt) * 64;
#pragma unroll
        for (int ni = 0; ni < 4; ++ni)  // 4 x 32B bursts -> full 128B line
          rowp[(ni << 4) + colL] = (__bf16)((acc[mi][ni][j] + bv[ni]) * mul);
      }
    }
  } else {
    float bv[4];
#pragma unroll
    for (int ni = 0; ni < 4; ++ni) bv[ni] = bias[n0 + (wc << 6) + (ni << 4) + colL];
#pragma unroll
    for (int mi = 0; mi < 4; ++mi) {
#pragma unroll
      for (int j = 0; j < 4; ++j) {
        const int Rm = m0 + (mi << 4) + (g << 2) + j;
        float* rowp = outF + (size_t)Rm * N + n0 + (wc << 6);
#pragma unroll
        for (int ni = 0; ni < 4; ++ni)
          rowp[(ni << 4) + colL] = acc[mi][ni][j] + bv[ni];
      }
    }
  }
}

// ---------------- V [bh, t, 64] -> Vt [bh, 64, t] (64x64 tiles via LDS) ----------------
__global__ __launch_bounds__(256) void transpose_v(const __bf16* __restrict__ Vb,
                                                   __bf16* __restrict__ Vt) {
  const int blk = blockIdx.x;
  const int bh = blk >> 5;
  const int t0 = (blk & 31) << 6;
  __shared__ __align__(16) __bf16 ts[64][72];
  const int tid = threadIdx.x;
  const __bf16* src = Vb + ((size_t)bh * 2048 + t0) * 64;
#pragma unroll
  for (int it = 0; it < 2; ++it) {
    int c = tid + (it << 8);
    int r = c >> 3, q8 = (c & 7) << 3;
    *(bf16x8*)&ts[r][q8] = *(const bf16x8*)(src + r * 64 + q8);
  }
  __syncthreads();
  __bf16* dst = Vt + (size_t)bh * 64 * 2048 + t0;
#pragma unroll
  for (int it = 0; it < 2; ++it) {
    int c = tid + (it << 8);
    int d = c >> 3, j8 = (c & 7) << 3;
    bf16x8 o;
#pragma unroll
    for (int e = 0; e < 8; ++e) o[e] = ts[j8 + e][d];
    *(bf16x8*)(dst + (size_t)d * 2048 + j8) = o;
  }
}

// ---------------- windowed attention ----------------
__global__ __launch_bounds__(256) void attn_win(const __bf16* __restrict__ Qb,
                                                const __bf16* __restrict__ Kb,
                                                const __bf16* __restrict__ Vt,
                                                __bf16* __restrict__ Ob) {
  const int bh = blockIdx.x >> 5;
  const int qb = blockIdx.x & 31;
  const int b = bh >> 4, h = bh & 15;
  __shared__ __align__(16) unsigned char Qs[64 * 128];
  __shared__ __align__(16) unsigned char Ks[128 * 128];
  __shared__ __align__(16) unsigned char Vs[64 * 256];
  __shared__ __align__(16) unsigned char Ps[4 * 16 * 272];
  const int tid = threadIdx.x;
  const int lane = tid & 63;
  const int w = tid >> 6;
  const int colL = lane & 15, g = lane >> 4;
  const __bf16* Qg = Qb + (size_t)bh * 2048 * 64;
  const __bf16* Kg = Kb + (size_t)bh * 2048 * 64;
  const __bf16* Vg = Vt + (size_t)bh * 64 * 2048;
  const int t0 = qb * 64 - 64;

#pragma unroll
  for (int it = 0; it < 2; ++it) {
    int c = tid + (it << 8);
    int r = c >> 3, p = c & 7, q = p ^ (r & 7);
    GLOAD16(Qg + (size_t)(qb * 64 + r) * 64 + (q << 3), Qs + c * 16);
  }
#pragma unroll
  for (int it = 0; it < 4; ++it) {
    int c = tid + (it << 8);
    int r = c >> 3, p = c & 7, q = p ^ (r & 7);
    int tok = t0 + r;
    tok = tok < 0 ? 0 : tok;
    GLOAD16(Kg + (size_t)tok * 64 + (q << 3), Ks + c * 16);
  }
#pragma unroll
  for (int it = 0; it < 4; ++it) {
    int c = tid + (it << 8);
    int r = c >> 4, p = c & 15, q = p ^ (r & 7);
    int tk = t0 + (q << 3);
    tk = tk < 0 ? 0 : tk;
    GLOAD16(Vg + (size_t)r * 2048 + tk, Vs + c * 16);
  }
  __syncthreads();

  f32x4 sc[8] = {};
  bf16x8 qf[2];
#pragma unroll
  for (int kk = 0; kk < 2; ++kk) {
    int r = (w << 4) + colL;
    int slot = (kk << 2) + g;
    qf[kk] = *(const bf16x8*)(Qs + r * 128 + ((slot ^ (r & 7)) << 4));
  }
#pragma unroll
  for (int ni = 0; ni < 8; ++ni) {
#pragma unroll
    for (int kk = 0; kk < 2; ++kk) {
      int r = (ni << 4) + colL;
      int slot = (kk << 2) + g;
      bf16x8 kf = *(const bf16x8*)(Ks + r * 128 + ((slot ^ (r & 7)) << 4));
      sc[ni] = MFMA16(qf[kk], kf, sc[ni]);
    }
  }

  float mx[4], sm[4];
#pragma unroll
  for (int j = 0; j < 4; ++j) mx[j] = -3.0e38f;
#pragma unroll
  for (int ni = 0; ni < 8; ++ni) {
#pragma unroll
    for (int j = 0; j < 4; ++j) {
      const int qi = (w << 4) + (g << 2) + j;
      const int ki = (ni << 4) + colL;
      const bool valid = (ki > qi) && (ki <= qi + 64) && (qb > 0 || ki >= 64);
      if (!valid) sc[ni][j] = -3.0e38f;
      mx[j] = fmaxf(mx[j], sc[ni][j]);
    }
  }
#pragma unroll
  for (int j = 0; j < 4; ++j) {
    mx[j] = fmaxf(mx[j], __shfl_xor(mx[j], 1));
    mx[j] = fmaxf(mx[j], __shfl_xor(mx[j], 2));
    mx[j] = fmaxf(mx[j], __shfl_xor(mx[j], 4));
    mx[j] = fmaxf(mx[j], __shfl_xor(mx[j], 8));
    sm[j] = 0.0f;
  }
  unsigned char* ps = Ps + w * (16 * 272);
#pragma unroll
  for (int ni = 0; ni < 8; ++ni) {
#pragma unroll
    for (int j = 0; j < 4; ++j) {
      float p = __expf(sc[ni][j] - mx[j]);
      sm[j] += p;
      *(__bf16*)(ps + ((g << 2) + j) * 272 + (((ni << 4) + colL) << 1)) = (__bf16)p;
    }
  }
#pragma unroll
  for (int j = 0; j < 4; ++j) {
    sm[j] += __shfl_xor(sm[j], 1);
    sm[j] += __shfl_xor(sm[j], 2);
    sm[j] += __shfl_xor(sm[j], 4);
    sm[j] += __shfl_xor(sm[j], 8);
  }
  __syncthreads();

  f32x4 o[4] = {};
#pragma unroll
  for (int step = 0; step < 4; ++step) {
    bf16x8 pf = *(const bf16x8*)(ps + colL * 272 + (step << 6) + (g << 4));
#pragma unroll
    for (int dt = 0; dt < 4; ++dt) {
      int r = (dt << 4) + colL;
      int slot = (step << 2) + g;
      bf16x8 vf = *(const bf16x8*)(Vs + r * 256 + ((slot ^ (r & 7)) << 4));
      o[dt] = MFMA16(pf, vf, o[dt]);
    }
  }

  float rinv[4];
#pragma unroll
  for (int j = 0; j < 4; ++j) rinv[j] = 1.0f / sm[j];
#pragma unroll
  for (int dt = 0; dt < 4; ++dt) {
#pragma unroll
    for (int j = 0; j < 4; ++j) {
      const int t = qb * 64 + (w << 4) + (g << 2) + j;
      Ob[((size_t)b * 2048 + t) * 1024 + h * 64 + (dt << 4) + colL] =
          (__bf16)(o[dt][j] * rinv[j]);
    }
  }
}

extern "C" void kernel_launch(void* const* d_in, const int* in_sizes, int n_in,
                              void* d_out, int out_size, void* d_ws, size_t ws_size,
                              hipStream_t stream) {
  const float* x = (const float*)d_in[0];     // [2,2048,1024]
  const float* Wqkv = (const float*)d_in[1];  // [3072,1024]
  const float* bqkv = (const float*)d_in[2];  // [3072]
  const float* Wout = (const float*)d_in[3];  // [1024,1024]
  const float* bout = (const float*)d_in[4];  // [1024]
  float* out = (float*)d_out;                 // [2,2048,1024] fp32

  __bf16* xb = (__bf16*)d_ws;             // 4194304
  __bf16* Wqkvb = xb + 4194304;           // 3145728
  __bf16* Woutb = Wqkvb + 3145728;        // 1048576
  __bf16* Qb = Woutb + 1048576;           // 4194304 each: [B,H,2048,64]
  __bf16* Kb = Qb + 4194304;
  __bf16* Vb = Kb + 4194304;
  __bf16* Vtb = Vb + 4194304;             // [B,H,64,2048]
  __bf16* AOb = Vtb + 4194304;            // attn out [B,2048,1024]

  cvt3<<<4096, 256, 0, stream>>>(x, Wqkv, Wout, xb, Wqkvb, Woutb);
  gemm_db<0><<<1536, 128, 0, stream>>>(xb, Wqkvb, bqkv, 4096, 3072, 1024,
                                       nullptr, Qb, Kb, Vb, 24, 192);
  transpose_v<<<1024, 256, 0, stream>>>(Vb, Vtb);
  attn_win<<<1024, 256, 0, stream>>>(Qb, Kb, Vtb, AOb);
  gemm_db<1><<<512, 128, 0, stream>>>(AOb, Woutb, bout, 4096, 1024, 1024,
                                      out, nullptr, nullptr, nullptr, 8, 64);
}

// Round 8
// 72.871 us; speedup vs baseline: 1.3821x; 1.3821x over previous
//
#include <hip/hip_runtime.h>
#include <hip/hip_bf16.h>

// LocalCausalAttention: B=2, N=2048, D=1024, H=16, DH=64, WINDOW=64
// out = ( softmax(mask(QK^T*0.125)) V ) Wout^T + bout,  QKV = x Wqkv^T + bqkv
//
// R8: BK=64 counted-vmcnt double-buffer (R6 structure, 2x MFMA per step) for both
//     GEMMs + V transposed through LDS in the QKV epilogue (transpose_v deleted).
//   QKV: 128^2 tile, 64KB LDS, 256 thr, grid 768 (2 blocks/CU co-res, backfilled).
//   outproj: 64x128 tile, 48KB LDS, 128 thr, grid 512 (all co-resident).
//   Per step t: {16 ds_read_b128 ; 32 MFMA ; lgkmcnt(0) ; bar ;
//                stage tile t+2 -> buf[t&1] ; vmcnt(NSTG) ; bar}   (R6-verified ledger)
//   Swizzle: 8 slots/128B row, slot q = p ^ (row&7), linear LDS dest (R1-proven, 0 conf).
//   V epilogue: acc -> LDS [64][72] bf16 (pad -> <=2-way, free) -> t-major read ->
//   128B-coalesced stores into Vt[bh][64][2048].

typedef __attribute__((ext_vector_type(8))) __bf16 bf16x8;
typedef __attribute__((ext_vector_type(4))) float f32x4;

#define GLOAD16(g, l)                                              \
  __builtin_amdgcn_global_load_lds(                                \
      (const __attribute__((address_space(1))) void*)(g),          \
      (__attribute__((address_space(3))) void*)(l), 16, 0, 0)

#define MFMA16(a, b, c) __builtin_amdgcn_mfma_f32_16x16x32_bf16((a), (b), (c), 0, 0, 0)

// ---------------- fused fp32 -> bf16 convert (x, Wqkv, Wout) ----------------
__global__ __launch_bounds__(256) void cvt3(const float* __restrict__ x,
                                            const float* __restrict__ wqkv,
                                            const float* __restrict__ wout,
                                            __bf16* __restrict__ xb,
                                            __bf16* __restrict__ wqkvb,
                                            __bf16* __restrict__ woutb) {
  const int blk = blockIdx.x;
  const float* src;
  __bf16* dst;
  int i;
  if (blk < 2048) {            // x: 4194304 elems
    src = x; dst = xb; i = (blk * 256 + (int)threadIdx.x) * 8;
  } else if (blk < 3584) {     // Wqkv: 3145728 elems
    src = wqkv; dst = wqkvb; i = ((blk - 2048) * 256 + (int)threadIdx.x) * 8;
  } else {                     // Wout: 1048576 elems
    src = wout; dst = woutb; i = ((blk - 3584) * 256 + (int)threadIdx.x) * 8;
  }
  f32x4 a = *(const f32x4*)(src + i);
  f32x4 b = *(const f32x4*)(src + i + 4);
  bf16x8 o;
  o[0] = (__bf16)a[0]; o[1] = (__bf16)a[1]; o[2] = (__bf16)a[2]; o[3] = (__bf16)a[3];
  o[4] = (__bf16)b[0]; o[5] = (__bf16)b[1]; o[6] = (__bf16)b[2]; o[7] = (__bf16)b[3];
  *(bf16x8*)(dst + i) = o;
}

// ---------------- (WM*64) x 128 BK=64 counted-vmcnt dbuf GEMM ----------------
// C[m,n] = sum_k A[m,k]*Bw[n,k] + bias[n].  K=1024 fixed. WM*2 waves, per-wave 64x64.
// MODE 0 (WM=2): scatter Q(*0.125)/K [B,H,2048,64]; V via LDS-transpose -> Vt[bh][64][2048].
// MODE 1: fp32 out row-major + bias.
template <int MODE, int WM>
__global__ __launch_bounds__(WM * 128) void gemm_ct(
    const __bf16* __restrict__ A, const __bf16* __restrict__ Bw,
    const float* __restrict__ bias, int N,
    float* __restrict__ outF,
    __bf16* __restrict__ qo, __bf16* __restrict__ ko, __bf16* __restrict__ vt,
    int nbn, int chunk) {
  constexpr int K = 1024;
  constexpr int ASZ = WM * 8192;       // A half: WM*64 rows x 128B
  constexpr int BUF = ASZ + 16384;     // + B half: 128 rows x 128B
  __shared__ __align__(16) unsigned char Ls[2 * BUF];
  const int tid = threadIdx.x;
  const int lane = tid & 63;
  const int wid = tid >> 6;                      // 0..WM*2-1
  const int wr = (WM == 2) ? (wid >> 1) : 0;     // wave m-half
  const int wc = (WM == 2) ? (wid & 1) : wid;    // wave n-half
  const int colL = lane & 15, g = lane >> 4;

  // T1: XCD chunking (grid %8 == 0 -> bijective). n varies fastest inside chunk.
  int s = (int)blockIdx.x;
  s = (s & 7) * chunk + (s >> 3);
  const int m0 = (s / nbn) * (WM * 64), n0 = (s % nbn) * 128;

  const __bf16* Ap = A + (size_t)m0 * K;
  const __bf16* Bp = Bw + (size_t)n0 * K;

  // stage: linear LDS dest c*16; row=c>>3, slot p=c&7, source col q=p^(row&7) (R1-proven)
  auto stageA = [&](unsigned char* lds, int k0) {
#pragma unroll
    for (int it = 0; it < 4; ++it) {
      int c = tid + it * (WM * 128);
      int row = c >> 3, p = c & 7, q = p ^ (row & 7);
      GLOAD16(Ap + (size_t)row * K + k0 + (q << 3), lds + c * 16);
    }
  };
  auto stageB = [&](unsigned char* lds, int k0) {
#pragma unroll
    for (int it = 0; it < 8 / WM; ++it) {
      int c = tid + it * (WM * 128);
      int row = c >> 3, p = c & 7, q = p ^ (row & 7);
      GLOAD16(Bp + (size_t)row * K + k0 + (q << 3), lds + c * 16);
    }
  };

  f32x4 acc[4][4] = {};

  // prologue: tiles 0,1 into bufs 0,1 (NSTG = 4 + 8/WM gloads per tile)
  stageA(Ls, 0);
  stageB(Ls + ASZ, 0);
  stageA(Ls + BUF, 64);
  stageB(Ls + BUF + ASZ, 64);
  if constexpr (WM == 2) asm volatile("s_waitcnt vmcnt(8)" ::: "memory");
  else                   asm volatile("s_waitcnt vmcnt(12)" ::: "memory");
  __builtin_amdgcn_s_barrier();

  constexpr int nT = 16;  // K/64
  for (int t = 0; t < nT; ++t) {
    const unsigned char* Ab = Ls + (t & 1) * BUF;
    const unsigned char* Bb = Ab + ASZ;
    bf16x8 af[4][2], bf[4][2];
#pragma unroll
    for (int mi = 0; mi < 4; ++mi) {
      const int r = (wr << 6) + (mi << 4) + colL;
#pragma unroll
      for (int kk = 0; kk < 2; ++kk)
        af[mi][kk] = *(const bf16x8*)(Ab + r * 128 + ((((kk << 2) + g) ^ (r & 7)) << 4));
    }
#pragma unroll
    for (int ni = 0; ni < 4; ++ni) {
      const int r = (wc << 6) + (ni << 4) + colL;
#pragma unroll
      for (int kk = 0; kk < 2; ++kk)
        bf[ni][kk] = *(const bf16x8*)(Bb + r * 128 + ((((kk << 2) + g) ^ (r & 7)) << 4));
    }
#pragma unroll
    for (int mi = 0; mi < 4; ++mi)
#pragma unroll
      for (int ni = 0; ni < 4; ++ni) {
        acc[mi][ni] = MFMA16(af[mi][0], bf[ni][0], acc[mi][ni]);
        acc[mi][ni] = MFMA16(af[mi][1], bf[ni][1], acc[mi][ni]);
      }
    // all this wave's ds_reads completed before anyone may DMA-overwrite buf[cur]
    asm volatile("s_waitcnt lgkmcnt(0)" ::: "memory");
    __builtin_amdgcn_s_barrier();
    if (t < nT - 2) {
      const int kn = (t + 2) << 6;
      unsigned char* dst = Ls + (t & 1) * BUF;  // overwrite just-retired buffer
      stageA(dst, kn);
      stageB(dst + ASZ, kn);
      // in flight: tile t+1 (NSTG) + t+2 (NSTG); retire oldest -> t+1 validated
      if constexpr (WM == 2) asm volatile("s_waitcnt vmcnt(8)" ::: "memory");
      else                   asm volatile("s_waitcnt vmcnt(12)" ::: "memory");
    } else {
      asm volatile("s_waitcnt vmcnt(0)" ::: "memory");  // tail: drain last tile
    }
    __builtin_amdgcn_s_barrier();
  }

  // epilogue: C/D layout col=lane&15, row=(lane>>4)*4+reg (m89-verified)
  if (MODE == 0) {
    const int Cn0 = n0 + (wc << 6);               // wave's 64-col head: sx/h const
    const int sx = Cn0 >> 10, h = (Cn0 >> 6) & 15;
    float bv[4];
#pragma unroll
    for (int ni = 0; ni < 4; ++ni) bv[ni] = bias[Cn0 + (ni << 4) + colL];
    const int b = m0 >> 11;
    if (sx == 2) {
      // ---- V: transpose via LDS, write coalesced rows of Vt[bh][d][2048] ----
      unsigned char* wreg = Ls + wid * 9216;      // per-wave [64][72] bf16 (pad->2-way)
#pragma unroll
      for (int mi = 0; mi < 4; ++mi)
#pragma unroll
        for (int ni = 0; ni < 4; ++ni)
#pragma unroll
          for (int jp = 0; jp < 2; ++jp) {
            const int tt = (mi << 4) + (g << 2) + (jp << 1);
            const int d = (ni << 4) + colL;
            unsigned short u0 = __builtin_bit_cast(
                unsigned short, (__bf16)(acc[mi][ni][jp * 2] + bv[ni]));
            unsigned short u1 = __builtin_bit_cast(
                unsigned short, (__bf16)(acc[mi][ni][jp * 2 + 1] + bv[ni]));
            *(unsigned int*)(wreg + ((d * 72 + tt) << 1)) =
                (unsigned int)u0 | ((unsigned int)u1 << 16);
          }
      asm volatile("s_waitcnt lgkmcnt(0)" ::: "memory");
      const size_t vbase = (size_t)(b * 16 + h) * 64 * 2048;
      const int tg0 = (m0 & 2047) + (wr << 6);
#pragma unroll
      for (int i = 0; i < 32; ++i) {
        const int d = (i << 1) + (lane >> 5);
        const int toff = (lane & 31) << 1;
        unsigned int v = *(unsigned int*)(wreg + (d * 144 + ((lane & 31) << 2)));
        *(unsigned int*)((unsigned short*)vt + vbase + (size_t)d * 2048 + tg0 + toff) = v;
      }
    } else {
      __bf16* dst = (sx == 0) ? qo : ko;
      const float mul = (sx == 0) ? 0.125f : 1.0f;  // fold SCALE into Q (exact pow2)
#pragma unroll
      for (int mi = 0; mi < 4; ++mi) {
#pragma unroll
        for (int j = 0; j < 4; ++j) {
          const int Rm = m0 + (wr << 6) + (mi << 4) + (g << 2) + j;
          const int tt = Rm & 2047;
          __bf16* rowp = dst + (((size_t)b * 16 + h) * 2048 + tt) * 64;
#pragma unroll
          for (int ni = 0; ni < 4; ++ni)  // 4 x 32B bursts -> full 128B line
            rowp[(ni << 4) + colL] = (__bf16)((acc[mi][ni][j] + bv[ni]) * mul);
        }
      }
    }
  } else {
    float bv[4];
#pragma unroll
    for (int ni = 0; ni < 4; ++ni) bv[ni] = bias[n0 + (wc << 6) + (ni << 4) + colL];
#pragma unroll
    for (int mi = 0; mi < 4; ++mi) {
#pragma unroll
      for (int j = 0; j < 4; ++j) {
        const int Rm = m0 + (wr << 6) + (mi << 4) + (g << 2) + j;
        float* rowp = outF + (size_t)Rm * N + n0 + (wc << 6);
#pragma unroll
        for (int ni = 0; ni < 4; ++ni)
          rowp[(ni << 4) + colL] = acc[mi][ni][j] + bv[ni];
      }
    }
  }
}

// ---------------- windowed attention ----------------
__global__ __launch_bounds__(256) void attn_win(const __bf16* __restrict__ Qb,
                                                const __bf16* __restrict__ Kb,
                                                const __bf16* __restrict__ Vt,
                                                __bf16* __restrict__ Ob) {
  const int bh = blockIdx.x >> 5;
  const int qb = blockIdx.x & 31;
  const int b = bh >> 4, h = bh & 15;
  __shared__ __align__(16) unsigned char Qs[64 * 128];
  __shared__ __align__(16) unsigned char Ks[128 * 128];
  __shared__ __align__(16) unsigned char Vs[64 * 256];
  __shared__ __align__(16) unsigned char Ps[4 * 16 * 272];
  const int tid = threadIdx.x;
  const int lane = tid & 63;
  const int w = tid >> 6;
  const int colL = lane & 15, g = lane >> 4;
  const __bf16* Qg = Qb + (size_t)bh * 2048 * 64;
  const __bf16* Kg = Kb + (size_t)bh * 2048 * 64;
  const __bf16* Vg = Vt + (size_t)bh * 64 * 2048;
  const int t0 = qb * 64 - 64;

#pragma unroll
  for (int it = 0; it < 2; ++it) {
    int c = tid + (it << 8);
    int r = c >> 3, p = c & 7, q = p ^ (r & 7);
    GLOAD16(Qg + (size_t)(qb * 64 + r) * 64 + (q << 3), Qs + c * 16);
  }
#pragma unroll
  for (int it = 0; it < 4; ++it) {
    int c = tid + (it << 8);
    int r = c >> 3, p = c & 7, q = p ^ (r & 7);
    int tok = t0 + r;
    tok = tok < 0 ? 0 : tok;
    GLOAD16(Kg + (size_t)tok * 64 + (q << 3), Ks + c * 16);
  }
#pragma unroll
  for (int it = 0; it < 4; ++it) {
    int c = tid + (it << 8);
    int r = c >> 4, p = c & 15, q = p ^ (r & 7);
    int tk = t0 + (q << 3);
    tk = tk < 0 ? 0 : tk;
    GLOAD16(Vg + (size_t)r * 2048 + tk, Vs + c * 16);
  }
  __syncthreads();

  f32x4 sc[8] = {};
  bf16x8 qf[2];
#pragma unroll
  for (int kk = 0; kk < 2; ++kk) {
    int r = (w << 4) + colL;
    int slot = (kk << 2) + g;
    qf[kk] = *(const bf16x8*)(Qs + r * 128 + ((slot ^ (r & 7)) << 4));
  }
#pragma unroll
  for (int ni = 0; ni < 8; ++ni) {
#pragma unroll
    for (int kk = 0; kk < 2; ++kk) {
      int r = (ni << 4) + colL;
      int slot = (kk << 2) + g;
      bf16x8 kf = *(const bf16x8*)(Ks + r * 128 + ((slot ^ (r & 7)) << 4));
      sc[ni] = MFMA16(qf[kk], kf, sc[ni]);
    }
  }

  float mx[4], sm[4];
#pragma unroll
  for (int j = 0; j < 4; ++j) mx[j] = -3.0e38f;
#pragma unroll
  for (int ni = 0; ni < 8; ++ni) {
#pragma unroll
    for (int j = 0; j < 4; ++j) {
      const int qi = (w << 4) + (g << 2) + j;
      const int ki = (ni << 4) + colL;
      const bool valid = (ki > qi) && (ki <= qi + 64) && (qb > 0 || ki >= 64);
      if (!valid) sc[ni][j] = -3.0e38f;
      mx[j] = fmaxf(mx[j], sc[ni][j]);
    }
  }
#pragma unroll
  for (int j = 0; j < 4; ++j) {
    mx[j] = fmaxf(mx[j], __shfl_xor(mx[j], 1));
    mx[j] = fmaxf(mx[j], __shfl_xor(mx[j], 2));
    mx[j] = fmaxf(mx[j], __shfl_xor(mx[j], 4));
    mx[j] = fmaxf(mx[j], __shfl_xor(mx[j], 8));
    sm[j] = 0.0f;
  }
  unsigned char* ps = Ps + w * (16 * 272);
#pragma unroll
  for (int ni = 0; ni < 8; ++ni) {
#pragma unroll
    for (int j = 0; j < 4; ++j) {
      float p = __expf(sc[ni][j] - mx[j]);
      sm[j] += p;
      *(__bf16*)(ps + ((g << 2) + j) * 272 + (((ni << 4) + colL) << 1)) = (__bf16)p;
    }
  }
#pragma unroll
  for (int j = 0; j < 4; ++j) {
    sm[j] += __shfl_xor(sm[j], 1);
    sm[j] += __shfl_xor(sm[j], 2);
    sm[j] += __shfl_xor(sm[j], 4);
    sm[j] += __shfl_xor(sm[j], 8);
  }
  __syncthreads();

  f32x4 o[4] = {};
#pragma unroll
  for (int step = 0; step < 4; ++step) {
    bf16x8 pf = *(const bf16x8*)(ps + colL * 272 + (step << 6) + (g << 4));
#pragma unroll
    for (int dt = 0; dt < 4; ++dt) {
      int r = (dt << 4) + colL;
      int slot = (step << 2) + g;
      bf16x8 vf = *(const bf16x8*)(Vs + r * 256 + ((slot ^ (r & 7)) << 4));
      o[dt] = MFMA16(pf, vf, o[dt]);
    }
  }

  float rinv[4];
#pragma unroll
  for (int j = 0; j < 4; ++j) rinv[j] = 1.0f / sm[j];
#pragma unroll
  for (int dt = 0; dt < 4; ++dt) {
#pragma unroll
    for (int j = 0; j < 4; ++j) {
      const int t = qb * 64 + (w << 4) + (g << 2) + j;
      Ob[((size_t)b * 2048 + t) * 1024 + h * 64 + (dt << 4) + colL] =
          (__bf16)(o[dt][j] * rinv[j]);
    }
  }
}

extern "C" void kernel_launch(void* const* d_in, const int* in_sizes, int n_in,
                              void* d_out, int out_size, void* d_ws, size_t ws_size,
                              hipStream_t stream) {
  const float* x = (const float*)d_in[0];     // [2,2048,1024]
  const float* Wqkv = (const float*)d_in[1];  // [3072,1024]
  const float* bqkv = (const float*)d_in[2];  // [3072]
  const float* Wout = (const float*)d_in[3];  // [1024,1024]
  const float* bout = (const float*)d_in[4];  // [1024]
  float* out = (float*)d_out;                 // [2,2048,1024] fp32

  __bf16* xb = (__bf16*)d_ws;             // 4194304
  __bf16* Wqkvb = xb + 4194304;           // 3145728
  __bf16* Woutb = Wqkvb + 3145728;        // 1048576
  __bf16* Qb = Woutb + 1048576;           // 4194304 each: [B,H,2048,64]
  __bf16* Kb = Qb + 4194304;
  __bf16* Vtb = Kb + 4194304;             // [B,H,64,2048] (written transposed by gemm)
  __bf16* AOb = Vtb + 4194304;            // attn out [B,2048,1024]

  cvt3<<<4096, 256, 0, stream>>>(x, Wqkv, Wout, xb, Wqkvb, Woutb);
  gemm_ct<0, 2><<<768, 256, 0, stream>>>(xb, Wqkvb, bqkv, 3072, nullptr,
                                         Qb, Kb, Vtb, 24, 96);
  attn_win<<<1024, 256, 0, stream>>>(Qb, Kb, Vtb, AOb);
  gemm_ct<1, 1><<<512, 128, 0, stream>>>(AOb, Woutb, bout, 1024, out,
                                         nullptr, nullptr, nullptr, 8, 64);
}